// Round 4
// baseline (597.448 us; speedup 1.0000x reference)
//
#include <hip/hip_runtime.h>
#include <hip/hip_bf16.h>

#define NN 50000
#define NE 800000
#define MPAD 50048   // 391 * 128 (layer-2 GEMM padding)
#define NBLK 196     // ceil(NN/256)

typedef __attribute__((ext_vector_type(8))) short short8;
typedef __attribute__((ext_vector_type(4))) float f32x4;
typedef __attribute__((ext_vector_type(2))) float f32x2;
typedef __attribute__((ext_vector_type(2))) unsigned short us2;
typedef __attribute__((ext_vector_type(4))) unsigned short us4;
typedef __attribute__((ext_vector_type(8))) unsigned short us8;

static __device__ __forceinline__ unsigned short f2bf(float f) {
    union { float f; unsigned int u; } v; v.f = f;
    unsigned int u = v.u;
    return (unsigned short)((u + 0x7FFFu + ((u >> 16) & 1u)) >> 16);  // RNE
}
static __device__ __forceinline__ float bf2f(unsigned short h) {
    union { unsigned int u; float f; } v; v.u = ((unsigned int)h) << 16;
    return v.f;
}

// ---------------- degrees ----------------
__global__ void k_deg(const int* __restrict__ src, const int* __restrict__ dst,
                      int* __restrict__ degO, int* __restrict__ degI) {
    int i = blockIdx.x * 256 + threadIdx.x;
    if (i < NE) {
        atomicAdd(&degO[src[i]], 1);
        atomicAdd(&degI[dst[i]], 1);
    }
}

// norms + per-block degI sums (fused k_norm + k_bsum)
__global__ void k_normsum(const int* __restrict__ degO, const int* __restrict__ degI,
                          float* __restrict__ nS, float* __restrict__ nD,
                          int* __restrict__ bsum) {
    int i = blockIdx.x * 256 + threadIdx.x;
    int v = 0;
    if (i < NN) {
        int o = degO[i], d = degI[i];
        nS[i] = 1.0f / sqrtf((float)(o > 0 ? o : 1));
        nD[i] = 1.0f / sqrtf((float)(d > 0 ? d : 1));
        v = d;
    }
#pragma unroll
    for (int o = 32; o >= 1; o >>= 1) v += __shfl_xor(v, o, 64);
    __shared__ int ws[4];
    if ((threadIdx.x & 63) == 0) ws[threadIdx.x >> 6] = v;
    __syncthreads();
    if (threadIdx.x == 0) bsum[blockIdx.x] = ws[0] + ws[1] + ws[2] + ws[3];
}

// ---------------- CSR build ----------------
static __device__ __forceinline__ int wave_iscan(int v, int lane) {
#pragma unroll
    for (int o = 1; o < 64; o <<= 1) {
        int x = __shfl_up(v, o, 64);
        if (lane >= o) v += x;
    }
    return v;
}

__global__ void k_bscan(const int* __restrict__ bsum, int* __restrict__ bofs) {
    int t = threadIdx.x;
    int v = (t < NBLK) ? bsum[t] : 0;
    int lane = t & 63, w = t >> 6;
    int inc = wave_iscan(v, lane);
    __shared__ int ws[4];
    if (lane == 63) ws[w] = inc;
    __syncthreads();
    int add = 0;
    for (int i = 0; i < w; i++) add += ws[i];
    if (t < NBLK) bofs[t] = add + inc - v;
}

__global__ void k_rowptr(const int* __restrict__ degI, const int* __restrict__ bofs,
                         int* __restrict__ rowptr) {
    int i = blockIdx.x * 256 + threadIdx.x;
    int v = (i < NN) ? degI[i] : 0;
    int lane = threadIdx.x & 63, w = threadIdx.x >> 6;
    int inc = wave_iscan(v, lane);
    __shared__ int ws[4];
    if (lane == 63) ws[w] = inc;
    __syncthreads();
    int add = 0;
    for (int k = 0; k < w; k++) add += ws[k];
    if (i < NN) rowptr[i] = bofs[blockIdx.x] + add + inc - v;
    if (i == 0) rowptr[NN] = NE;
}

__global__ void k_sort(const int* __restrict__ src, const int* __restrict__ dst,
                       const int* __restrict__ rowptr, int* __restrict__ fill,
                       int* __restrict__ eidx) {
    int e = blockIdx.x * 256 + threadIdx.x;
    if (e < NE) {
        int d = dst[e];
        int p = rowptr[d] + atomicAdd(&fill[d], 1);
        eidx[p] = src[e];
    }
}

// ---------------- bf16 conversions ----------------
// all three weight matrices in one launch
__global__ void k_cvtW3(const float* __restrict__ W0, const float* __restrict__ W1,
                        const float* __restrict__ W2,
                        unsigned short* __restrict__ W0b, unsigned short* __restrict__ W1b,
                        unsigned short* __restrict__ W2b) {
    int i = blockIdx.x * 256 + threadIdx.x;
    if (i < 65536) W0b[i] = f2bf(W0[i]);
    else if (i < 131072) W1b[i - 65536] = f2bf(W1[i - 65536]);
    else if (i < 163840) W2b[i - 131072] = f2bf(W2[i - 131072]);
}

__global__ void k_cvt0(const float* __restrict__ x, const float* __restrict__ nS,
                       unsigned short* __restrict__ xb) {
    int row = blockIdx.x; int t = threadIdx.x;
    float s = nS[row];
    xb[(long)row * 256 + t] = f2bf(x[(long)row * 256 + t] * s);
}

// ---------------- FUSED gather-aggregate + GEMM (layers 0/1) ----------------
// Block: 64 dst nodes x 256 out cols, 256 threads (4 waves).
// Phase 1: wave w aggregates nodes bm+w*16..+15 into LDS A-tile (bf16, nD folded).
// Phase 2: 64x256x256 MFMA GEMM from LDS; epilogue: h=relu(acc+b) f32, xbn=f2bf(h*nS).
__global__ __launch_bounds__(256) void k_fused(const int* __restrict__ rowptr,
                                               const int* __restrict__ eidx,
                                               const unsigned short* __restrict__ xb,
                                               const float* __restrict__ nD,
                                               const unsigned short* __restrict__ B,
                                               const float* __restrict__ bias,
                                               const float* __restrict__ nS,
                                               float* __restrict__ outF,
                                               unsigned short* __restrict__ xbn) {
    __shared__ unsigned short As[64][260];   // pad 260: bank stride 130%32=2 -> conflict-free frag reads
    __shared__ unsigned short Bs[256][36];   // [col][k] for current 32-k chunk
    const int bm = blockIdx.x * 64;
    const int tid = threadIdx.x;
    const int lane = tid & 63;
    const int w = tid >> 6;

    // ---- phase 1: gather-aggregate into As ----
    {
        const int c = lane * 4;
        for (int it = 0; it < 16; ++it) {
            int ln = w * 16 + it;
            int node = bm + ln;
            if (node < NN) {
                const int e0 = rowptr[node], e1 = rowptr[node + 1];
                f32x4 acc = {0.f, 0.f, 0.f, 0.f};
                int j = e0;
                for (; j + 4 <= e1; j += 4) {
                    int s0 = eidx[j], s1 = eidx[j + 1], s2 = eidx[j + 2], s3 = eidx[j + 3];
                    us4 v0 = *(const us4*)&xb[(long)s0 * 256 + c];
                    us4 v1 = *(const us4*)&xb[(long)s1 * 256 + c];
                    us4 v2 = *(const us4*)&xb[(long)s2 * 256 + c];
                    us4 v3 = *(const us4*)&xb[(long)s3 * 256 + c];
#pragma unroll
                    for (int k = 0; k < 4; k++)
                        acc[k] += (bf2f(v0[k]) + bf2f(v1[k])) + (bf2f(v2[k]) + bf2f(v3[k]));
                }
                for (; j < e1; j++) {
                    us4 v = *(const us4*)&xb[(long)eidx[j] * 256 + c];
#pragma unroll
                    for (int k = 0; k < 4; k++) acc[k] += bf2f(v[k]);
                }
                float nd = nD[node];
                us4 o;
#pragma unroll
                for (int k = 0; k < 4; k++) o[k] = f2bf(acc[k] * nd);
                *(us4*)&As[ln][c] = o;
            } else {
                *(us4*)&As[ln][c] = (us4){0, 0, 0, 0};
            }
        }
    }
    __syncthreads();

    // ---- phase 2: GEMM ----
    const int wr = w >> 1, wc = w & 1;   // wave: rows wr*32..+31, cols wc*128..+127
    f32x4 acc[2][8];
#pragma unroll
    for (int m = 0; m < 2; m++)
#pragma unroll
        for (int n = 0; n < 8; n++) acc[m][n] = (f32x4){0.f, 0.f, 0.f, 0.f};

    for (int kt = 0; kt < 256; kt += 32) {
        // stage Bs: thread t covers k = (t>>4) and (t>>4)+16, cols (t&15)*16..+15
        {
            int k0 = tid >> 4, c0 = (tid & 15) * 16;
#pragma unroll
            for (int kk = 0; kk < 2; ++kk) {
                int k = k0 + kk * 16;
                const unsigned short* g = &B[(long)(kt + k) * 256 + c0];
                us8 v0 = *(const us8*)(g);
                us8 v1 = *(const us8*)(g + 8);
#pragma unroll
                for (int j = 0; j < 8; j++) Bs[c0 + j][k] = v0[j];
#pragma unroll
                for (int j = 0; j < 8; j++) Bs[c0 + 8 + j][k] = v1[j];
            }
        }
        __syncthreads();

        union U { us4 h[2]; short8 s; };
        const int kb = (lane >> 4) * 4;
        short8 af[2], bf[8];
#pragma unroll
        for (int m = 0; m < 2; m++) {
            int r = wr * 32 + m * 16 + (lane & 15);
            U u; u.h[0] = *(const us4*)&As[r][kt + kb]; u.h[1] = *(const us4*)&As[r][kt + kb + 16];
            af[m] = u.s;
        }
#pragma unroll
        for (int n = 0; n < 8; n++) {
            int cidx = wc * 128 + n * 16 + (lane & 15);
            U u; u.h[0] = *(const us4*)&Bs[cidx][kb]; u.h[1] = *(const us4*)&Bs[cidx][kb + 16];
            bf[n] = u.s;
        }
#pragma unroll
        for (int m = 0; m < 2; m++)
#pragma unroll
            for (int n = 0; n < 8; n++)
                acc[m][n] = __builtin_amdgcn_mfma_f32_16x16x32_bf16(af[m], bf[n], acc[m][n], 0, 0, 0);
        __syncthreads();
    }

    // ---- epilogue ----
#pragma unroll
    for (int m = 0; m < 2; m++) {
        int rbase = bm + wr * 32 + m * 16 + (lane >> 4) * 4;
#pragma unroll
        for (int n = 0; n < 8; n++) {
            int cidx = wc * 128 + n * 16 + (lane & 15);
            float bb = bias[cidx];
#pragma unroll
            for (int j = 0; j < 4; j++) {
                int row = rbase + j;
                if (row < NN) {
                    float v = fmaxf(acc[m][n][j] + bb, 0.f);
                    outF[(long)row * 256 + cidx] = v;
                    xbn[(long)row * 256 + cidx] = f2bf(v * nS[row]);
                } else if (row < MPAD) {
                    xbn[(long)row * 256 + cidx] = 0;
                }
            }
        }
    }
}

// ---------------- layer-2 GEMM (transform-first): A [MPAD][256], B [256][128] -> bf16 hgb ----------------
__global__ __launch_bounds__(256) void k_gemm2(const unsigned short* __restrict__ A,
                                               const unsigned short* __restrict__ B,
                                               unsigned short* __restrict__ outB) {
    __shared__ unsigned short As[128][40];
    __shared__ unsigned short Bs[128][40];
    const int bm = blockIdx.x * 128;
    const int tid = threadIdx.x;
    const int lane = tid & 63;
    const int w = tid >> 6;
    const int wr = w >> 1, wc = w & 1;

    f32x4 acc[4][4];
#pragma unroll
    for (int m = 0; m < 4; m++)
#pragma unroll
        for (int n = 0; n < 4; n++) acc[m][n] = (f32x4){0.f, 0.f, 0.f, 0.f};

    for (int kt = 0; kt < 256; kt += 32) {
        {
            int r = tid >> 1, c = (tid & 1) * 16;
            const unsigned short* g = &A[(long)(bm + r) * 256 + kt + c];
            *(us8*)&As[r][c]     = *(const us8*)(g);
            *(us8*)&As[r][c + 8] = *(const us8*)(g + 8);
        }
        {
            int k = tid >> 3, c0 = (tid & 7) * 16;
            const unsigned short* g = &B[(long)(kt + k) * 128 + c0];
            us8 v0 = *(const us8*)(g);
            us8 v1 = *(const us8*)(g + 8);
#pragma unroll
            for (int j = 0; j < 8; j++) Bs[c0 + j][k] = v0[j];
#pragma unroll
            for (int j = 0; j < 8; j++) Bs[c0 + 8 + j][k] = v1[j];
        }
        __syncthreads();

        union U { us4 h[2]; short8 s; };
        const int kb = (lane >> 4) * 4;
        short8 af[4], bf[4];
#pragma unroll
        for (int m = 0; m < 4; m++) {
            int r = wr * 64 + m * 16 + (lane & 15);
            U u; u.h[0] = *(const us4*)&As[r][kb]; u.h[1] = *(const us4*)&As[r][kb + 16];
            af[m] = u.s;
        }
#pragma unroll
        for (int n = 0; n < 4; n++) {
            int cidx = wc * 64 + n * 16 + (lane & 15);
            U u; u.h[0] = *(const us4*)&Bs[cidx][kb]; u.h[1] = *(const us4*)&Bs[cidx][kb + 16];
            bf[n] = u.s;
        }
#pragma unroll
        for (int m = 0; m < 4; m++)
#pragma unroll
            for (int n = 0; n < 4; n++)
                acc[m][n] = __builtin_amdgcn_mfma_f32_16x16x32_bf16(af[m], bf[n], acc[m][n], 0, 0, 0);
        __syncthreads();
    }

#pragma unroll
    for (int m = 0; m < 4; m++) {
        int rbase = bm + wr * 64 + m * 16 + (lane >> 4) * 4;
#pragma unroll
        for (int n = 0; n < 4; n++) {
            int cidx = wc * 64 + n * 16 + (lane & 15);
#pragma unroll
            for (int j = 0; j < 4; j++)
                outB[(long)(rbase + j) * 128 + cidx] = f2bf(acc[m][n][j]);
        }
    }
}

// ---------------- layer-2 post-GEMM aggregation (128-wide bf16) ----------------
__global__ __launch_bounds__(256) void k_agg2(const int* __restrict__ rowptr,
                                              const int* __restrict__ eidx,
                                              const unsigned short* __restrict__ hgb,
                                              const float* __restrict__ nD,
                                              const float* __restrict__ b,
                                              float* __restrict__ h2,
                                              float* __restrict__ h2b) {
    const int node = blockIdx.x * 4 + (threadIdx.x >> 6);
    const int lane = threadIdx.x & 63;
    if (node >= NN) return;
    const int c = lane * 2;
    const int e0 = rowptr[node], e1 = rowptr[node + 1];
    f32x2 acc = {0.f, 0.f};
    int j = e0;
    for (; j + 4 <= e1; j += 4) {
        int s0 = eidx[j], s1 = eidx[j + 1], s2 = eidx[j + 2], s3 = eidx[j + 3];
        us2 v0 = *(const us2*)&hgb[(long)s0 * 128 + c];
        us2 v1 = *(const us2*)&hgb[(long)s1 * 128 + c];
        us2 v2 = *(const us2*)&hgb[(long)s2 * 128 + c];
        us2 v3 = *(const us2*)&hgb[(long)s3 * 128 + c];
#pragma unroll
        for (int k = 0; k < 2; k++)
            acc[k] += (bf2f(v0[k]) + bf2f(v1[k])) + (bf2f(v2[k]) + bf2f(v3[k]));
    }
    for (; j < e1; j++) {
        us2 v = *(const us2*)&hgb[(long)eidx[j] * 128 + c];
#pragma unroll
        for (int k = 0; k < 2; k++) acc[k] += bf2f(v[k]);
    }
    float nd = nD[node];
    f32x2 v;
    v[0] = acc[0] * nd + b[c];
    v[1] = acc[1] * nd + b[c + 1];
    *(f32x2*)&h2[(long)node * 128 + c] = v;
    *(f32x2*)&h2b[(long)node * 128 + c] = v;
}

extern "C" void kernel_launch(void* const* d_in, const int* in_sizes, int n_in,
                              void* d_out, int out_size, void* d_ws, size_t ws_size,
                              hipStream_t stream) {
    const float* feats = (const float*)d_in[0];
    const int*   src   = (const int*)d_in[1];
    const int*   dst   = (const int*)d_in[2];
    const float* W0 = (const float*)d_in[3];
    const float* b0 = (const float*)d_in[4];
    const float* W1 = (const float*)d_in[5];
    const float* b1 = (const float*)d_in[6];
    const float* W2 = (const float*)d_in[7];
    const float* b2 = (const float*)d_in[8];

    float* out = (float*)d_out;
    float* h0  = out;
    float* h1  = out + (long)NN * 256;
    float* h2  = out + 2L * NN * 256;
    float* h2b = out + 2L * NN * 256 + (long)NN * 128;

    char* ws = (char*)d_ws;
    size_t off = 0;
    auto alloc = [&](size_t bytes) { void* p = ws + off; off += (bytes + 255) & ~255UL; return p; };
    unsigned short* xb   = (unsigned short*)alloc((size_t)MPAD * 256 * 2);
    unsigned short* xb2  = (unsigned short*)alloc((size_t)MPAD * 256 * 2);
    unsigned short* hgb  = (unsigned short*)alloc((size_t)MPAD * 128 * 2);
    unsigned short* W0b = (unsigned short*)alloc(256 * 256 * 2);
    unsigned short* W1b = (unsigned short*)alloc(256 * 256 * 2);
    unsigned short* W2b = (unsigned short*)alloc(256 * 128 * 2);
    int*   degO   = (int*)alloc(NN * 4);
    int*   degI   = (int*)alloc(NN * 4);
    float* nS     = (float*)alloc(NN * 4);
    float* nD     = (float*)alloc(NN * 4);
    int*   rowptr = (int*)alloc((NN + 1) * 4);
    int*   bsum   = (int*)alloc(NBLK * 4);
    int*   bofs   = (int*)alloc(NBLK * 4);
    int*   fill   = (int*)alloc(NN * 4);
    int*   eidx   = (int*)alloc((size_t)NE * 4);

    // degrees + norms (+ block sums for scan)
    hipMemsetAsync(degO, 0, NN * 4, stream);
    hipMemsetAsync(degI, 0, NN * 4, stream);
    hipMemsetAsync(fill, 0, NN * 4, stream);
    k_deg<<<(NE + 255) / 256, 256, 0, stream>>>(src, dst, degO, degI);
    k_normsum<<<NBLK, 256, 0, stream>>>(degO, degI, nS, nD, bsum);

    // CSR (by dst)
    k_bscan<<<1, 256, 0, stream>>>(bsum, bofs);
    k_rowptr<<<NBLK, 256, 0, stream>>>(degI, bofs, rowptr);
    k_sort<<<(NE + 255) / 256, 256, 0, stream>>>(src, dst, rowptr, fill, eidx);

    // weights -> bf16 (one launch)
    k_cvtW3<<<(163840 + 255) / 256, 256, 0, stream>>>(W0, W1, W2, W0b, W1b, W2b);

    // layer 0 input: xb = feats * nS (bf16), NN rows only (gather never reads pad rows)
    k_cvt0<<<NN, 256, 0, stream>>>(feats, nS, xb);

    // ---- layer 0: fused aggregate+GEMM ----
    k_fused<<<MPAD / 64, 256, 0, stream>>>(rowptr, eidx, xb, nD, W0b, b0, nS, h0, xb2);

    // ---- layer 1: fused aggregate+GEMM ----
    k_fused<<<MPAD / 64, 256, 0, stream>>>(rowptr, eidx, xb2, nD, W1b, b1, nS, h1, xb);

    // ---- layer 2: transform-first (gather 128-wide) ----
    k_gemm2<<<MPAD / 128, 256, 0, stream>>>(xb, W2b, hgb);
    k_agg2<<<(NN + 3) / 4, 256, 0, stream>>>(rowptr, eidx, hgb, nD, b2, h2, h2b);
}

// Round 5
// 404.630 us; speedup vs baseline: 1.4765x; 1.4765x over previous
//
#include <hip/hip_runtime.h>
#include <hip/hip_bf16.h>

#define NN 50000
#define NE 800000
#define MPAD 50048   // 391 * 128 (layer-2 GEMM padding)
#define NBLK 196     // ceil(NN/256)

typedef __attribute__((ext_vector_type(8))) short short8;
typedef __attribute__((ext_vector_type(4))) float f32x4;
typedef __attribute__((ext_vector_type(4))) unsigned short us4;
typedef __attribute__((ext_vector_type(8))) unsigned short us8;

static __device__ __forceinline__ unsigned short f2bf(float f) {
    union { float f; unsigned int u; } v; v.f = f;
    unsigned int u = v.u;
    return (unsigned short)((u + 0x7FFFu + ((u >> 16) & 1u)) >> 16);  // RNE
}
static __device__ __forceinline__ float bf2f(unsigned short h) {
    union { unsigned int u; float f; } v; v.u = ((unsigned int)h) << 16;
    return v.f;
}

// ---------------- degrees ----------------
__global__ void k_deg(const int* __restrict__ src, const int* __restrict__ dst,
                      int* __restrict__ degO, int* __restrict__ degI) {
    int i = blockIdx.x * 256 + threadIdx.x;
    if (i < NE) {
        atomicAdd(&degO[src[i]], 1);
        atomicAdd(&degI[dst[i]], 1);
    }
}

// norms + per-block degI sums (fused norm + bsum)
__global__ void k_normsum(const int* __restrict__ degO, const int* __restrict__ degI,
                          float* __restrict__ nS, float* __restrict__ nD,
                          int* __restrict__ bsum) {
    int i = blockIdx.x * 256 + threadIdx.x;
    int v = 0;
    if (i < NN) {
        int o = degO[i], d = degI[i];
        nS[i] = 1.0f / sqrtf((float)(o > 0 ? o : 1));
        nD[i] = 1.0f / sqrtf((float)(d > 0 ? d : 1));
        v = d;
    }
#pragma unroll
    for (int o = 32; o >= 1; o >>= 1) v += __shfl_xor(v, o, 64);
    __shared__ int ws[4];
    if ((threadIdx.x & 63) == 0) ws[threadIdx.x >> 6] = v;
    __syncthreads();
    if (threadIdx.x == 0) bsum[blockIdx.x] = ws[0] + ws[1] + ws[2] + ws[3];
}

// ---------------- CSR build ----------------
static __device__ __forceinline__ int wave_iscan(int v, int lane) {
#pragma unroll
    for (int o = 1; o < 64; o <<= 1) {
        int x = __shfl_up(v, o, 64);
        if (lane >= o) v += x;
    }
    return v;
}

__global__ void k_bscan(const int* __restrict__ bsum, int* __restrict__ bofs) {
    int t = threadIdx.x;
    int v = (t < NBLK) ? bsum[t] : 0;
    int lane = t & 63, w = t >> 6;
    int inc = wave_iscan(v, lane);
    __shared__ int ws[4];
    if (lane == 63) ws[w] = inc;
    __syncthreads();
    int add = 0;
    for (int i = 0; i < w; i++) add += ws[i];
    if (t < NBLK) bofs[t] = add + inc - v;
}

// rowptr + fill (fill starts as a copy of rowptr; k_sort bumps it directly)
__global__ void k_rowptr(const int* __restrict__ degI, const int* __restrict__ bofs,
                         int* __restrict__ rowptr, int* __restrict__ fill) {
    int i = blockIdx.x * 256 + threadIdx.x;
    int v = (i < NN) ? degI[i] : 0;
    int lane = threadIdx.x & 63, w = threadIdx.x >> 6;
    int inc = wave_iscan(v, lane);
    __shared__ int ws[4];
    if (lane == 63) ws[w] = inc;
    __syncthreads();
    int add = 0;
    for (int k = 0; k < w; k++) add += ws[k];
    if (i < NN) {
        int r = bofs[blockIdx.x] + add + inc - v;
        rowptr[i] = r;
        fill[i] = r;
    }
    if (i == 0) rowptr[NN] = NE;
}

__global__ void k_sort(const int* __restrict__ src, const int* __restrict__ dst,
                       int* __restrict__ fill, int* __restrict__ eidx) {
    int e = blockIdx.x * 256 + threadIdx.x;
    if (e < NE) {
        int p = atomicAdd(&fill[dst[e]], 1);
        eidx[p] = src[e];
    }
}

// ---------------- bf16 weight conversion, TRANSPOSED: WT[c][k] = W[k][c] ----------------
__global__ void k_cvtW3T(const float* __restrict__ W0, const float* __restrict__ W1,
                         const float* __restrict__ W2,
                         unsigned short* __restrict__ W0T, unsigned short* __restrict__ W1T,
                         unsigned short* __restrict__ W2T) {
    int i = blockIdx.x * 256 + threadIdx.x;
    if (i < 65536) {
        int k = i >> 8, c = i & 255;
        W0T[c * 256 + k] = f2bf(W0[i]);
    } else if (i < 131072) {
        int j = i - 65536;
        int k = j >> 8, c = j & 255;
        W1T[c * 256 + k] = f2bf(W1[j]);
    } else if (i < 163840) {
        int j = i - 131072;
        int k = j >> 7, c = j & 127;
        W2T[c * 256 + k] = f2bf(W2[j]);
    }
}

__global__ void k_cvt0(const float* __restrict__ x, const float* __restrict__ nS,
                       unsigned short* __restrict__ xb) {
    int row = blockIdx.x; int t = threadIdx.x;
    float s = nS[row];
    xb[(long)row * 256 + t] = f2bf(x[(long)row * 256 + t] * s);
}

// ---------------- gather-aggregate (256-wide bf16), 2 edges per load inst ----------------
// one wave per dst node; lane-halves own edge j / j+1; lane owns 8 cols (16 B loads).
__global__ __launch_bounds__(256) void k_aggb(const int* __restrict__ rowptr,
                                              const int* __restrict__ eidx,
                                              const unsigned short* __restrict__ xb,
                                              const float* __restrict__ nD,
                                              unsigned short* __restrict__ aggb) {
    const int node = blockIdx.x * 4 + (threadIdx.x >> 6);
    const int lane = threadIdx.x & 63;
    const int half = lane >> 5;
    const int c = (lane & 31) * 8;          // ushort col base
    if (node >= NN) {
        if (node < MPAD && half == 0)
            *(us8*)&aggb[(long)node * 256 + c] = (us8){0,0,0,0,0,0,0,0};
        return;
    }
    const int e0 = rowptr[node], e1 = rowptr[node + 1];
    float acc[8] = {0.f,0.f,0.f,0.f,0.f,0.f,0.f,0.f};
    int j = e0;
    for (; j + 4 <= e1; j += 4) {           // 4 edges, 2 loads in flight
        int sA = __builtin_nontemporal_load(&eidx[j + half]);
        int sB = __builtin_nontemporal_load(&eidx[j + 2 + half]);
        us8 vA = *(const us8*)&xb[(long)sA * 256 + c];
        us8 vB = *(const us8*)&xb[(long)sB * 256 + c];
#pragma unroll
        for (int k = 0; k < 8; k++) acc[k] += bf2f(vA[k]) + bf2f(vB[k]);
    }
    if (j + 2 <= e1) {
        int sA = __builtin_nontemporal_load(&eidx[j + half]);
        us8 vA = *(const us8*)&xb[(long)sA * 256 + c];
#pragma unroll
        for (int k = 0; k < 8; k++) acc[k] += bf2f(vA[k]);
        j += 2;
    }
    if (j < e1 && half == 0) {              // single leftover edge
        int sA = __builtin_nontemporal_load(&eidx[j]);
        us8 vA = *(const us8*)&xb[(long)sA * 256 + c];
#pragma unroll
        for (int k = 0; k < 8; k++) acc[k] += bf2f(vA[k]);
    }
#pragma unroll
    for (int k = 0; k < 8; k++) acc[k] += __shfl_xor(acc[k], 32, 64);
    if (half == 0) {
        float nd = nD[node];
        us8 o;
#pragma unroll
        for (int k = 0; k < 8; k++) o[k] = f2bf(acc[k] * nd);
        *(us8*)&aggb[(long)node * 256 + c] = o;
    }
}

// ---------------- GEMM: A [MPAD][256] bf16, BT [NOUT][256] bf16 (transposed weights) ----
// MODE 0: h = relu(acc + b) -> outF f32 NT-store (row<NN); xbn = f2bf(h*nS) (pad rows -> 0)
// MODE 1: outB = f2bf(acc)  (raw, no bias)
template<int NOUT, int MODE>
__global__ __launch_bounds__(256) void k_gemm(const unsigned short* __restrict__ A,
                                              const unsigned short* __restrict__ BT,
                                              const float* __restrict__ bias,
                                              const float* __restrict__ nS,
                                              float* __restrict__ outF,
                                              unsigned short* __restrict__ xbn,
                                              unsigned short* __restrict__ outB) {
    __shared__ unsigned short As[128][40];
    __shared__ unsigned short Bs[128][36];   // [col][k], staged from BT row-copies
    const int bm = blockIdx.x * 128;
    const int bn = blockIdx.y * 128;
    const int tid = threadIdx.x;
    const int lane = tid & 63;
    const int w = tid >> 6;
    const int wr = w >> 1, wc = w & 1;

    f32x4 acc[4][4];
#pragma unroll
    for (int m = 0; m < 4; m++)
#pragma unroll
        for (int n = 0; n < 4; n++) acc[m][n] = (f32x4){0.f, 0.f, 0.f, 0.f};

    for (int kt = 0; kt < 256; kt += 32) {
        {   // A tile: thread t -> row t>>1, 16 ushorts at (t&1)*16
            int r = tid >> 1, c = (tid & 1) * 16;
            const unsigned short* g = &A[(long)(bm + r) * 256 + kt + c];
            *(us8*)&As[r][c]     = *(const us8*)(g);
            *(us8*)&As[r][c + 8] = *(const us8*)(g + 8);
        }
        {   // B tile: thread t -> col t>>1, 16 contiguous k at (t&1)*16 (row-copy, conflict-free)
            int col = tid >> 1, kh = (tid & 1) * 16;
            const unsigned short* g = &BT[(long)(bn + col) * 256 + kt + kh];
            *(us8*)&Bs[col][kh]     = *(const us8*)(g);
            *(us8*)&Bs[col][kh + 8] = *(const us8*)(g + 8);
        }
        __syncthreads();

        union U { us4 h[2]; short8 s; };
        const int kb = (lane >> 4) * 4;
        short8 af[4], bf[4];
#pragma unroll
        for (int m = 0; m < 4; m++) {
            int r = wr * 64 + m * 16 + (lane & 15);
            U u; u.h[0] = *(const us4*)&As[r][kb]; u.h[1] = *(const us4*)&As[r][kb + 16];
            af[m] = u.s;
        }
#pragma unroll
        for (int n = 0; n < 4; n++) {
            int cl = wc * 64 + n * 16 + (lane & 15);
            U u; u.h[0] = *(const us4*)&Bs[cl][kb]; u.h[1] = *(const us4*)&Bs[cl][kb + 16];
            bf[n] = u.s;
        }
#pragma unroll
        for (int m = 0; m < 4; m++)
#pragma unroll
            for (int n = 0; n < 4; n++)
                acc[m][n] = __builtin_amdgcn_mfma_f32_16x16x32_bf16(af[m], bf[n], acc[m][n], 0, 0, 0);
        __syncthreads();
    }

#pragma unroll
    for (int m = 0; m < 4; m++) {
        int rbase = bm + wr * 64 + m * 16 + (lane >> 4) * 4;
#pragma unroll
        for (int n = 0; n < 4; n++) {
            int gc = bn + wc * 64 + n * 16 + (lane & 15);
            float bb = (MODE == 0) ? bias[gc] : 0.f;
#pragma unroll
            for (int j = 0; j < 4; j++) {
                int row = rbase + j;
                if (MODE == 0) {
                    if (row < NN) {
                        float v = fmaxf(acc[m][n][j] + bb, 0.f);
                        __builtin_nontemporal_store(v, &outF[(long)row * 256 + gc]);
                        xbn[(long)row * 256 + gc] = f2bf(v * nS[row]);
                    } else {
                        xbn[(long)row * 256 + gc] = 0;
                    }
                } else {
                    outB[(long)row * NOUT + gc] = f2bf(acc[m][n][j]);
                }
            }
        }
    }
}

// ---------------- layer-2 aggregation (128-wide bf16), 4 edges per load inst ----------------
__global__ __launch_bounds__(256) void k_agg2(const int* __restrict__ rowptr,
                                              const int* __restrict__ eidx,
                                              const unsigned short* __restrict__ hgb,
                                              const float* __restrict__ nD,
                                              const float* __restrict__ b,
                                              float* __restrict__ h2,
                                              float* __restrict__ h2b) {
    const int node = blockIdx.x * 4 + (threadIdx.x >> 6);
    const int lane = threadIdx.x & 63;
    if (node >= NN) return;
    const int q = lane >> 4;                // quarter: edge slot
    const int c = (lane & 15) * 8;          // ushort col base
    const int e0 = rowptr[node], e1 = rowptr[node + 1];
    float acc[8] = {0.f,0.f,0.f,0.f,0.f,0.f,0.f,0.f};
    int j = e0;
    for (; j + 8 <= e1; j += 8) {
        int sA = __builtin_nontemporal_load(&eidx[j + q]);
        int sB = __builtin_nontemporal_load(&eidx[j + 4 + q]);
        us8 vA = *(const us8*)&hgb[(long)sA * 128 + c];
        us8 vB = *(const us8*)&hgb[(long)sB * 128 + c];
#pragma unroll
        for (int k = 0; k < 8; k++) acc[k] += bf2f(vA[k]) + bf2f(vB[k]);
    }
    if (j + 4 <= e1) {
        int sA = __builtin_nontemporal_load(&eidx[j + q]);
        us8 vA = *(const us8*)&hgb[(long)sA * 128 + c];
#pragma unroll
        for (int k = 0; k < 8; k++) acc[k] += bf2f(vA[k]);
        j += 4;
    }
    if (j < e1 && q < (e1 - j)) {           // 1..3 leftover edges
        int sA = __builtin_nontemporal_load(&eidx[j + q]);
        us8 vA = *(const us8*)&hgb[(long)sA * 128 + c];
#pragma unroll
        for (int k = 0; k < 8; k++) acc[k] += bf2f(vA[k]);
    }
#pragma unroll
    for (int k = 0; k < 8; k++) acc[k] += __shfl_xor(acc[k], 16, 64);
#pragma unroll
    for (int k = 0; k < 8; k++) acc[k] += __shfl_xor(acc[k], 32, 64);
    if (q == 0) {
        float nd = nD[node];
        f32x4 v0, v1;
#pragma unroll
        for (int k = 0; k < 4; k++) v0[k] = acc[k] * nd + b[c + k];
#pragma unroll
        for (int k = 0; k < 4; k++) v1[k] = acc[4 + k] * nd + b[c + 4 + k];
        __builtin_nontemporal_store(v0, (f32x4*)&h2[(long)node * 128 + c]);
        __builtin_nontemporal_store(v1, (f32x4*)&h2[(long)node * 128 + c + 4]);
        __builtin_nontemporal_store(v0, (f32x4*)&h2b[(long)node * 128 + c]);
        __builtin_nontemporal_store(v1, (f32x4*)&h2b[(long)node * 128 + c + 4]);
    }
}

extern "C" void kernel_launch(void* const* d_in, const int* in_sizes, int n_in,
                              void* d_out, int out_size, void* d_ws, size_t ws_size,
                              hipStream_t stream) {
    const float* feats = (const float*)d_in[0];
    const int*   src   = (const int*)d_in[1];
    const int*   dst   = (const int*)d_in[2];
    const float* W0 = (const float*)d_in[3];
    const float* b0 = (const float*)d_in[4];
    const float* W1 = (const float*)d_in[5];
    const float* b1 = (const float*)d_in[6];
    const float* W2 = (const float*)d_in[7];
    const float* b2 = (const float*)d_in[8];

    float* out = (float*)d_out;
    float* h0  = out;
    float* h1  = out + (long)NN * 256;
    float* h2  = out + 2L * NN * 256;
    float* h2b = out + 2L * NN * 256 + (long)NN * 128;

    char* ws = (char*)d_ws;
    size_t off = 0;
    auto alloc = [&](size_t bytes) { void* p = ws + off; off += (bytes + 255) & ~255UL; return p; };
    unsigned short* xb   = (unsigned short*)alloc((size_t)MPAD * 256 * 2);
    unsigned short* xb2  = (unsigned short*)alloc((size_t)MPAD * 256 * 2);
    unsigned short* aggb = (unsigned short*)alloc((size_t)MPAD * 256 * 2);
    unsigned short* hgb  = (unsigned short*)alloc((size_t)MPAD * 128 * 2);
    unsigned short* W0T = (unsigned short*)alloc(256 * 256 * 2);
    unsigned short* W1T = (unsigned short*)alloc(256 * 256 * 2);
    unsigned short* W2T = (unsigned short*)alloc(128 * 256 * 2);
    int*   degO   = (int*)alloc(NN * 4);
    int*   degI   = (int*)alloc(NN * 4);
    float* nS     = (float*)alloc(NN * 4);
    float* nD     = (float*)alloc(NN * 4);
    int*   rowptr = (int*)alloc((NN + 1) * 4);
    int*   bsum   = (int*)alloc(NBLK * 4);
    int*   bofs   = (int*)alloc(NBLK * 4);
    int*   fill   = (int*)alloc(NN * 4);
    int*   eidx   = (int*)alloc((size_t)NE * 4);

    // degrees + norms
    hipMemsetAsync(degO, 0, NN * 4, stream);
    hipMemsetAsync(degI, 0, NN * 4, stream);
    k_deg<<<(NE + 255) / 256, 256, 0, stream>>>(src, dst, degO, degI);
    k_normsum<<<NBLK, 256, 0, stream>>>(degO, degI, nS, nD, bsum);

    // CSR (by dst)
    k_bscan<<<1, 256, 0, stream>>>(bsum, bofs);
    k_rowptr<<<NBLK, 256, 0, stream>>>(degI, bofs, rowptr, fill);
    k_sort<<<(NE + 255) / 256, 256, 0, stream>>>(src, dst, fill, eidx);

    // weights -> bf16 transposed
    k_cvtW3T<<<(163840 + 255) / 256, 256, 0, stream>>>(W0, W1, W2, W0T, W1T, W2T);

    // layer 0 input: xb = feats * nS (bf16)
    k_cvt0<<<NN, 256, 0, stream>>>(feats, nS, xb);

    // ---- layer 0 ----
    k_aggb<<<MPAD / 4, 256, 0, stream>>>(rowptr, eidx, xb, nD, aggb);
    k_gemm<256, 0><<<dim3(MPAD / 128, 2), 256, 0, stream>>>(aggb, W0T, b0, nS, h0, xb2, nullptr);

    // ---- layer 1 ----
    k_aggb<<<MPAD / 4, 256, 0, stream>>>(rowptr, eidx, xb2, nD, aggb);
    k_gemm<256, 0><<<dim3(MPAD / 128, 2), 256, 0, stream>>>(aggb, W1T, b1, nS, h1, xb, nullptr);

    // ---- layer 2: transform-first (gather 128-wide) ----
    k_gemm<128, 1><<<dim3(MPAD / 128, 1), 256, 0, stream>>>(xb, W2T, nullptr, nullptr, nullptr, nullptr, hgb);
    k_agg2<<<(NN + 3) / 4, 256, 0, stream>>>(rowptr, eidx, hgb, nD, b2, h2, h2b);
}